// Round 1
// baseline (557.652 us; speedup 1.0000x reference)
//
#include <hip/hip_runtime.h>
#include <hip/hip_bf16.h>
#include <math.h>

// Problem constants (from reference setup_inputs)
#define BB 16
#define CC 3
#define HH 512
#define WW 1024
#define NN (HH * WW)          // 524288 = 2^19
#define BN ((size_t)BB * NN)  // 8388608 = 2^23

// ws layout (bytes):
//   0    : double sum_tw
//   16   : double acc[2]  (log_sum, sq_sum)
//   32   : uint   cnts[2] (n_nz, n_zz)
//   48   : int    nval[16]
//   128  : int    counts[16*64]   (chunk counts -> exclusive offsets)
//   8192 : uint   mask[BN/32]     (invalid bits)  1 MB
//   2MB  : int    pos_list[BN]    33.5 MB
// total ~35.7 MB

__device__ __forceinline__ float tw_at(const float* __restrict__ img, int b, int h, int w) {
    const float* p = img + (size_t)b * CC * NN + (size_t)h * WW + w;
    float a0 = p[0], a1 = p[NN], a2 = p[2 * NN];
    float tw = 0.f;
    if (w < WW - 1) {
        float s = fabsf(a0 - p[1]) + fabsf(a1 - p[NN + 1]) + fabsf(a2 - p[2 * NN + 1]);
        tw += s / 3.0f;
    }
    if (h < HH - 1) {
        float s = fabsf(a0 - p[WW]) + fabsf(a1 - p[NN + WW]) + fabsf(a2 - p[2 * NN + WW]);
        tw += s / 3.0f;
    }
    return tw * 0.5f;
}

__global__ void tw_sum_kernel(const float* __restrict__ img, double* __restrict__ sum_out) {
    size_t stride = (size_t)gridDim.x * blockDim.x;
    double acc = 0.0;
    for (size_t g = (size_t)blockIdx.x * blockDim.x + threadIdx.x; g < BN; g += stride) {
        int w = (int)(g & (WW - 1));
        int h = (int)((g >> 10) & (HH - 1));
        int b = (int)(g >> 19);
        acc += (double)tw_at(img, b, h, w);
    }
    // block reduce
    int lane = threadIdx.x & 63, wid = threadIdx.x >> 6;
    for (int o = 32; o > 0; o >>= 1) acc += __shfl_down(acc, o);
    __shared__ double sd[4];
    if (lane == 0) sd[wid] = acc;
    __syncthreads();
    if (threadIdx.x == 0) atomicAdd(sum_out, sd[0] + sd[1] + sd[2] + sd[3]);
}

__global__ void mask_kernel(const float* __restrict__ img, const double* __restrict__ sum_tw,
                            unsigned int* __restrict__ mask) {
    float mean = (float)(*sum_tw / (double)BN);
    size_t stride = (size_t)gridDim.x * blockDim.x;
    for (size_t g = (size_t)blockIdx.x * blockDim.x + threadIdx.x; g < BN; g += stride) {
        int w = (int)(g & (WW - 1));
        int h = (int)((g >> 10) & (HH - 1));
        int b = (int)(g >> 19);
        float tw = tw_at(img, b, h, w);
        int invalid = tw < mean;
        unsigned long long bal = __ballot(invalid);
        int lane = threadIdx.x & 63;
        if (lane == 0)  mask[g >> 5]       = (unsigned int)(bal & 0xFFFFFFFFull);
        if (lane == 32) mask[g >> 5]       = (unsigned int)(bal >> 32);
    }
}

// One block (256 threads) per 8192-element chunk; each thread owns one 32-bit word.
__global__ void count_kernel(const unsigned int* __restrict__ mask, int* __restrict__ counts) {
    int c = blockIdx.x;             // global chunk id, 0..1023
    int t = threadIdx.x;
    unsigned int wbits = ~mask[(size_t)c * 256 + t];  // valid bits
    int cnt = __popc(wbits);
    int lane = t & 63, wid = t >> 6;
    for (int o = 32; o > 0; o >>= 1) cnt += __shfl_down(cnt, o);
    __shared__ int s[4];
    if (lane == 0) s[wid] = cnt;
    __syncthreads();
    if (t == 0) counts[c] = s[0] + s[1] + s[2] + s[3];
}

// 16 waves, one per batch row; scan 64 chunk counts -> exclusive offsets + nval
__global__ void scan_kernel(int* __restrict__ counts, int* __restrict__ nval) {
    int lane = threadIdx.x & 63;
    int row = threadIdx.x >> 6;
    int v = counts[row * 64 + lane];
    int incl = v;
    for (int o = 1; o < 64; o <<= 1) {
        int n = __shfl_up(incl, o);
        if (lane >= o) incl += n;
    }
    counts[row * 64 + lane] = incl - v;   // exclusive
    if (lane == 63) nval[row] = incl;
}

__global__ void scatter_kernel(const unsigned int* __restrict__ mask,
                               const int* __restrict__ offsets,
                               int* __restrict__ pos_list) {
    int cglob = blockIdx.x;        // 0..1023
    int b  = cglob >> 6;
    int cl = cglob & 63;
    int t = threadIdx.x;
    unsigned int wbits = ~mask[(size_t)cglob * 256 + t];  // valid bits
    int cnt = __popc(wbits);
    int lane = t & 63, wid = t >> 6;
    int incl = cnt;
    for (int o = 1; o < 64; o <<= 1) {
        int n = __shfl_up(incl, o);
        if (lane >= o) incl += n;
    }
    __shared__ int wsum[4];
    if (lane == 63) wsum[wid] = incl;
    __syncthreads();
    int woff = 0;
    for (int i = 0; i < wid; i++) woff += wsum[i];
    int excl = woff + incl - cnt;
    int rank = offsets[cglob] + excl;
    size_t outb = ((size_t)b << 19) + rank;
    int elemBase = cl * 8192 + t * 32;   // element index within row
    while (wbits) {
        int k = __ffs(wbits) - 1;
        pos_list[outb++] = elemBase + k;
        wbits &= wbits - 1;
    }
}

__global__ void loss_kernel(const float* __restrict__ pred, const float* __restrict__ gt,
                            const float* __restrict__ ur,
                            const unsigned int* __restrict__ mask,
                            const int* __restrict__ pos_list,
                            const int* __restrict__ nval,
                            double* __restrict__ acc, unsigned int* __restrict__ cnts) {
    size_t stride = (size_t)gridDim.x * blockDim.x;
    double ls = 0.0, ss = 0.0;
    unsigned int cnz = 0, czz = 0;
    for (size_t g = (size_t)blockIdx.x * blockDim.x + threadIdx.x; g < BN; g += stride) {
        unsigned int wb = mask[g >> 5];
        if ((wb >> (g & 31)) & 1u) {      // invalid pixel -> contributes to loss
            int b = (int)(g >> 19);
            size_t rowb = (size_t)b << 19;
            int nv = nval[b];
            float u_r = ur[g];
            int u = (int)(u_r * (float)nv);     // f32 mul, truncate (matches astype(int32))
            u = min(u, nv - 1);
            int p = pos_list[rowb + u];
            float gt_v = gt[rowb + p];
            float pr_v = pred[rowb + p];
            float gc = gt[g];
            float pc = pred[g];
            float r1 = gc / gt_v;
            float r2 = gt_v / gc;
            float d = pc - pr_v;
            if (r1 >= 1.02f) {            // target = +1, arg = -d
                ls += (double)log1pf(expf(-d)); cnz++;
            } else if (r2 > 1.02f) {      // target = -1, arg = +d
                ls += (double)log1pf(expf(d));  cnz++;
            } else {                      // target = 0
                ss += (double)(d * d);          czz++;
            }
        }
    }
    int lane = threadIdx.x & 63, wid = threadIdx.x >> 6;
    __shared__ double sd[4];
    __shared__ unsigned int si[4];
    for (int o = 32; o > 0; o >>= 1) ls += __shfl_down(ls, o);
    if (lane == 0) sd[wid] = ls;
    __syncthreads();
    if (threadIdx.x == 0) atomicAdd(&acc[0], sd[0] + sd[1] + sd[2] + sd[3]);
    __syncthreads();
    for (int o = 32; o > 0; o >>= 1) ss += __shfl_down(ss, o);
    if (lane == 0) sd[wid] = ss;
    __syncthreads();
    if (threadIdx.x == 0) atomicAdd(&acc[1], sd[0] + sd[1] + sd[2] + sd[3]);
    __syncthreads();
    for (int o = 32; o > 0; o >>= 1) cnz += __shfl_down(cnz, o);
    if (lane == 0) si[wid] = cnz;
    __syncthreads();
    if (threadIdx.x == 0) atomicAdd(&cnts[0], si[0] + si[1] + si[2] + si[3]);
    __syncthreads();
    for (int o = 32; o > 0; o >>= 1) czz += __shfl_down(czz, o);
    if (lane == 0) si[wid] = czz;
    __syncthreads();
    if (threadIdx.x == 0) atomicAdd(&cnts[1], si[0] + si[1] + si[2] + si[3]);
}

__global__ void finalize_kernel(const double* __restrict__ acc,
                                const unsigned int* __restrict__ cnts,
                                float* __restrict__ out) {
    if (threadIdx.x == 0) {
        out[0] = (float)(acc[0] / (double)cnts[0] + acc[1] / (double)cnts[1]);
    }
}

extern "C" void kernel_launch(void* const* d_in, const int* in_sizes, int n_in,
                              void* d_out, int out_size, void* d_ws, size_t ws_size,
                              hipStream_t stream) {
    const float* pred = (const float*)d_in[0];
    const float* gt   = (const float*)d_in[1];
    const float* img  = (const float*)d_in[2];
    const float* ur   = (const float*)d_in[3];
    float* out = (float*)d_out;

    char* ws = (char*)d_ws;
    double*       sum_tw = (double*)(ws + 0);
    double*       acc    = (double*)(ws + 16);
    unsigned int* cnts   = (unsigned int*)(ws + 32);
    int*          nval   = (int*)(ws + 48);
    int*          counts = (int*)(ws + 128);
    unsigned int* mask   = (unsigned int*)(ws + 8192);
    int*          pos    = (int*)(ws + (1 << 21));

    hipMemsetAsync(ws, 0, 8192, stream);
    tw_sum_kernel <<<2048, 256, 0, stream>>>(img, sum_tw);
    mask_kernel   <<<2048, 256, 0, stream>>>(img, sum_tw, mask);
    count_kernel  <<<1024, 256, 0, stream>>>(mask, counts);
    scan_kernel   <<<1, 1024, 0, stream>>>(counts, nval);
    scatter_kernel<<<1024, 256, 0, stream>>>(mask, counts, pos);
    loss_kernel   <<<2048, 256, 0, stream>>>(pred, gt, ur, mask, pos, nval, acc, cnts);
    finalize_kernel<<<1, 64, 0, stream>>>(acc, cnts, out);
}

// Round 2
// 319.712 us; speedup vs baseline: 1.7442x; 1.7442x over previous
//
#include <hip/hip_runtime.h>
#include <hip/hip_bf16.h>
#include <math.h>

#define BB 16
#define CC 3
#define HH 512
#define WW 1024
#define NN (HH * WW)          // 524288 = 2^19
#define BN ((size_t)BB * NN)  // 8388608 = 2^23

// ws layout (bytes):
//   0    : double sum_part[64]
//   512  : double acc_ls[64]
//   1024 : double acc_ss[64]
//   1536 : uint   cnt_nz[64]
//   1792 : uint   cnt_zz[64]
//   2048 : int    nval[16]
//   4096 : int    counts[1024]      (chunk counts -> exclusive offsets)
//   8192 : uint   mask[BN/32]       invalid bits, 1 MB
//   2MB  : float2 val_list[BN]      (gt_val, pred_val) compacted, 67 MB

// Compute tw for 4 consecutive pixels starting at g0 (g0 % 4 == 0).
__device__ __forceinline__ void tw4(const float* __restrict__ img, size_t g0, float out[4]) {
    int w0 = (int)(g0 & (WW - 1));
    int h  = (int)((g0 >> 10) & (HH - 1));
    int b  = (int)(g0 >> 19);
    const float* p = img + (size_t)b * CC * NN + (size_t)h * WW + w0;
    float c0[5], c1[5], c2[5], d0[4], d1[4], d2[4];
    float4 v;
    v = *(const float4*)p;            c0[0]=v.x; c0[1]=v.y; c0[2]=v.z; c0[3]=v.w;
    v = *(const float4*)(p + NN);     c1[0]=v.x; c1[1]=v.y; c1[2]=v.z; c1[3]=v.w;
    v = *(const float4*)(p + 2*NN);   c2[0]=v.x; c2[1]=v.y; c2[2]=v.z; c2[3]=v.w;
    bool haveR = (w0 < WW - 4);       // need element w0+4 only if gx for w0+3 exists
    c0[4] = haveR ? p[4]        : 0.f;
    c1[4] = haveR ? p[NN + 4]   : 0.f;
    c2[4] = haveR ? p[2*NN + 4] : 0.f;
    bool haveD = (h < HH - 1);
    if (haveD) {
        v = *(const float4*)(p + WW);          d0[0]=v.x; d0[1]=v.y; d0[2]=v.z; d0[3]=v.w;
        v = *(const float4*)(p + NN + WW);     d1[0]=v.x; d1[1]=v.y; d1[2]=v.z; d1[3]=v.w;
        v = *(const float4*)(p + 2*NN + WW);   d2[0]=v.x; d2[1]=v.y; d2[2]=v.z; d2[3]=v.w;
    } else {
        #pragma unroll
        for (int j = 0; j < 4; ++j) { d0[j] = 0.f; d1[j] = 0.f; d2[j] = 0.f; }
    }
    #pragma unroll
    for (int j = 0; j < 4; ++j) {
        float tw = 0.f;
        if (w0 + j < WW - 1)
            tw += (fabsf(c0[j]-c0[j+1]) + fabsf(c1[j]-c1[j+1]) + fabsf(c2[j]-c2[j+1])) / 3.0f;
        if (haveD)
            tw += (fabsf(c0[j]-d0[j]) + fabsf(c1[j]-d1[j]) + fabsf(c2[j]-d2[j])) / 3.0f;
        out[j] = tw * 0.5f;
    }
}

__global__ __launch_bounds__(256) void tw_sum_kernel(const float* __restrict__ img,
                                                     double* __restrict__ sum_part) {
    size_t g0 = ((size_t)blockIdx.x * 256 + threadIdx.x) * 4;
    float tw[4]; tw4(img, g0, tw);
    double acc = (double)((tw[0] + tw[1]) + (tw[2] + tw[3]));
    int lane = threadIdx.x & 63, wid = threadIdx.x >> 6;
    for (int o = 32; o > 0; o >>= 1) acc += __shfl_down(acc, o);
    __shared__ double sd[4];
    if (lane == 0) sd[wid] = acc;
    __syncthreads();
    if (threadIdx.x == 0) atomicAdd(&sum_part[blockIdx.x & 63], sd[0]+sd[1]+sd[2]+sd[3]);
}

__global__ __launch_bounds__(256) void mask_kernel(const float* __restrict__ img,
                                                   const double* __restrict__ sum_part,
                                                   unsigned int* __restrict__ mask,
                                                   int* __restrict__ counts) {
    __shared__ float s_mean;
    __shared__ unsigned int wds[32];
    __shared__ int sv[4];
    int t = threadIdx.x;
    if (t == 0) {
        double s = 0.0;
        for (int i = 0; i < 64; ++i) s += sum_part[i];
        s_mean = (float)(s / (double)BN);
    }
    if (t < 32) wds[t] = 0;
    __syncthreads();
    float mean = s_mean;
    size_t g0 = ((size_t)blockIdx.x * 256 + t) * 4;
    float tw[4]; tw4(img, g0, tw);
    unsigned int nib = 0;
    #pragma unroll
    for (int j = 0; j < 4; ++j) nib |= (tw[j] < mean ? 1u : 0u) << j;
    atomicOr(&wds[t >> 3], nib << ((t & 7) * 4));
    int cv = 4 - __popc(nib);   // valid count this thread
    int lane = t & 63, wid = t >> 6;
    for (int o = 32; o > 0; o >>= 1) cv += __shfl_down(cv, o);
    if (lane == 0) sv[wid] = cv;
    __syncthreads();
    if (t < 32) mask[(size_t)blockIdx.x * 32 + t] = wds[t];
    if (t == 0) atomicAdd(&counts[blockIdx.x >> 3], sv[0]+sv[1]+sv[2]+sv[3]);
}

// 16 waves, one per batch row; scan 64 chunk counts -> exclusive offsets + nval
__global__ void scan_kernel(int* __restrict__ counts, int* __restrict__ nval) {
    int lane = threadIdx.x & 63;
    int row = threadIdx.x >> 6;
    int v = counts[row * 64 + lane];
    int incl = v;
    for (int o = 1; o < 64; o <<= 1) {
        int n = __shfl_up(incl, o);
        if (lane >= o) incl += n;
    }
    counts[row * 64 + lane] = incl - v;   // exclusive
    if (lane == 63) nval[row] = incl;
}

// Writes val_list[rank] = (gt[pos], pred[pos]) for each valid pos, per row.
__global__ __launch_bounds__(256) void scatter_kernel(const unsigned int* __restrict__ mask,
                                                      const int* __restrict__ offsets,
                                                      const float* __restrict__ gt,
                                                      const float* __restrict__ pred,
                                                      float2* __restrict__ val) {
    int cglob = blockIdx.x;        // 0..1023 (chunk of 8192 px)
    int b  = cglob >> 6;
    int cl = cglob & 63;
    int t = threadIdx.x;
    unsigned int wbits = ~mask[(size_t)cglob * 256 + t];  // valid bits
    int cnt = __popc(wbits);
    int lane = t & 63, wid = t >> 6;
    int incl = cnt;
    for (int o = 1; o < 64; o <<= 1) {
        int n = __shfl_up(incl, o);
        if (lane >= o) incl += n;
    }
    __shared__ int wsum[4];
    if (lane == 63) wsum[wid] = incl;
    __syncthreads();
    int woff = 0;
    for (int i = 0; i < wid; i++) woff += wsum[i];
    int rank = offsets[cglob] + woff + incl - cnt;
    size_t rowb = (size_t)b << 19;
    size_t outb = rowb + rank;
    int elemBase = cl * 8192 + t * 32;
    while (wbits) {
        int k = __ffs(wbits) - 1;
        size_t e = rowb + elemBase + k;
        val[outb++] = make_float2(gt[e], pred[e]);
        wbits &= wbits - 1;
    }
}

__global__ __launch_bounds__(256) void loss_kernel(const float* __restrict__ pred,
                                                   const float* __restrict__ gt,
                                                   const float* __restrict__ ur,
                                                   const unsigned int* __restrict__ mask,
                                                   const float2* __restrict__ val,
                                                   const int* __restrict__ nv_arr,
                                                   double* __restrict__ acc_ls,
                                                   double* __restrict__ acc_ss,
                                                   unsigned int* __restrict__ cnt_nz,
                                                   unsigned int* __restrict__ cnt_zz) {
    int n = blockIdx.x * 256 + threadIdx.x;   // pixel index within a row, grid=2048
    double ls = 0.0, ss = 0.0;
    unsigned int cnz = 0, czz = 0;
    #pragma unroll
    for (int b = 0; b < BB; ++b) {
        size_t g = ((size_t)b << 19) + (size_t)n;
        if ((mask[g >> 5] >> (n & 31)) & 1u) {     // invalid pixel
            int nv = nv_arr[b];
            float u_r = ur[g];
            int u = min((int)(u_r * (float)nv), nv - 1);
            float2 v = val[((size_t)b << 19) + (size_t)u];
            float gc = gt[g], pc = pred[g];
            float d = pc - v.y;
            float r1 = gc / v.x, r2 = v.x / gc;
            if (r1 >= 1.02f)      { ls += (double)log1pf(expf(-d)); ++cnz; }
            else if (r2 > 1.02f)  { ls += (double)log1pf(expf( d)); ++cnz; }
            else                  { ss += (double)(d * d); ++czz; }
        }
    }
    int lane = threadIdx.x & 63, wid = threadIdx.x >> 6;
    __shared__ double sd[4];
    __shared__ unsigned int si[4];
    for (int o = 32; o > 0; o >>= 1) ls += __shfl_down(ls, o);
    if (lane == 0) sd[wid] = ls;
    __syncthreads();
    if (threadIdx.x == 0) atomicAdd(&acc_ls[blockIdx.x & 63], sd[0]+sd[1]+sd[2]+sd[3]);
    __syncthreads();
    for (int o = 32; o > 0; o >>= 1) ss += __shfl_down(ss, o);
    if (lane == 0) sd[wid] = ss;
    __syncthreads();
    if (threadIdx.x == 0) atomicAdd(&acc_ss[blockIdx.x & 63], sd[0]+sd[1]+sd[2]+sd[3]);
    __syncthreads();
    for (int o = 32; o > 0; o >>= 1) cnz += __shfl_down(cnz, o);
    if (lane == 0) si[wid] = cnz;
    __syncthreads();
    if (threadIdx.x == 0) atomicAdd(&cnt_nz[blockIdx.x & 63], si[0]+si[1]+si[2]+si[3]);
    __syncthreads();
    for (int o = 32; o > 0; o >>= 1) czz += __shfl_down(czz, o);
    if (lane == 0) si[wid] = czz;
    __syncthreads();
    if (threadIdx.x == 0) atomicAdd(&cnt_zz[blockIdx.x & 63], si[0]+si[1]+si[2]+si[3]);
}

__global__ void finalize_kernel(const double* __restrict__ acc_ls,
                                const double* __restrict__ acc_ss,
                                const unsigned int* __restrict__ cnt_nz,
                                const unsigned int* __restrict__ cnt_zz,
                                float* __restrict__ out) {
    int t = threadIdx.x;   // 64 threads
    double l = acc_ls[t], s2 = acc_ss[t];
    unsigned int a = cnt_nz[t], c = cnt_zz[t];
    for (int o = 32; o > 0; o >>= 1) {
        l  += __shfl_down(l, o);
        s2 += __shfl_down(s2, o);
        a  += __shfl_down(a, o);
        c  += __shfl_down(c, o);
    }
    if (t == 0) out[0] = (float)(l / (double)a + s2 / (double)c);
}

extern "C" void kernel_launch(void* const* d_in, const int* in_sizes, int n_in,
                              void* d_out, int out_size, void* d_ws, size_t ws_size,
                              hipStream_t stream) {
    const float* pred = (const float*)d_in[0];
    const float* gt   = (const float*)d_in[1];
    const float* img  = (const float*)d_in[2];
    const float* ur   = (const float*)d_in[3];
    float* out = (float*)d_out;

    char* ws = (char*)d_ws;
    double*       sum_part = (double*)(ws + 0);
    double*       acc_ls   = (double*)(ws + 512);
    double*       acc_ss   = (double*)(ws + 1024);
    unsigned int* cnt_nz   = (unsigned int*)(ws + 1536);
    unsigned int* cnt_zz   = (unsigned int*)(ws + 1792);
    int*          nval     = (int*)(ws + 2048);
    int*          counts   = (int*)(ws + 4096);
    unsigned int* mask     = (unsigned int*)(ws + 8192);
    float2*       val      = (float2*)(ws + (1 << 21));

    hipMemsetAsync(ws, 0, 8192, stream);
    tw_sum_kernel <<<8192, 256, 0, stream>>>(img, sum_part);
    mask_kernel   <<<8192, 256, 0, stream>>>(img, sum_part, mask, counts);
    scan_kernel   <<<1, 1024, 0, stream>>>(counts, nval);
    scatter_kernel<<<1024, 256, 0, stream>>>(mask, counts, gt, pred, val);
    loss_kernel   <<<2048, 256, 0, stream>>>(pred, gt, ur, mask, val, nval,
                                             acc_ls, acc_ss, cnt_nz, cnt_zz);
    finalize_kernel<<<1, 64, 0, stream>>>(acc_ls, acc_ss, cnt_nz, cnt_zz, out);
}

// Round 3
// 159.017 us; speedup vs baseline: 3.5069x; 2.0106x over previous
//
#include <hip/hip_runtime.h>
#include <hip/hip_bf16.h>
#include <math.h>

#define BB 16
#define CC 3
#define HH 512
#define WW 1024
#define NN (HH * WW)          // 524288 = 2^19
#define BN ((size_t)BB * NN)  // 8388608 = 2^23

// ws layout (bytes):
//   0    : double sum_part[64]
//   512  : double acc_ls[64]
//   1024 : double acc_ss[64]
//   1536 : uint   cnt_nz[64]
//   1792 : uint   cnt_zz[64]
//   2048 : int    nval[16]
//   4096 : int    counts[1024]      (chunk counts -> exclusive offsets)
//   8192 : uint   mask[BN/32]       invalid bits, 1 MB
//   2MB  : float2 val_list[BN]      (gt_val, pred_val) compacted, 67 MB
//          NOTE: the same region doubles as tw[BN] (f32, 33.5 MB) between
//          tw_sum_kernel and mask_kernel — scatter overwrites it later.

// Compute tw for 4 consecutive pixels starting at g0 (g0 % 4 == 0).
__device__ __forceinline__ void tw4(const float* __restrict__ img, size_t g0, float out[4]) {
    int w0 = (int)(g0 & (WW - 1));
    int h  = (int)((g0 >> 10) & (HH - 1));
    int b  = (int)(g0 >> 19);
    const float* p = img + (size_t)b * CC * NN + (size_t)h * WW + w0;
    float c0[5], c1[5], c2[5], d0[4], d1[4], d2[4];
    float4 v;
    v = *(const float4*)p;            c0[0]=v.x; c0[1]=v.y; c0[2]=v.z; c0[3]=v.w;
    v = *(const float4*)(p + NN);     c1[0]=v.x; c1[1]=v.y; c1[2]=v.z; c1[3]=v.w;
    v = *(const float4*)(p + 2*NN);   c2[0]=v.x; c2[1]=v.y; c2[2]=v.z; c2[3]=v.w;
    bool haveR = (w0 < WW - 4);
    c0[4] = haveR ? p[4]        : 0.f;
    c1[4] = haveR ? p[NN + 4]   : 0.f;
    c2[4] = haveR ? p[2*NN + 4] : 0.f;
    bool haveD = (h < HH - 1);
    if (haveD) {
        v = *(const float4*)(p + WW);          d0[0]=v.x; d0[1]=v.y; d0[2]=v.z; d0[3]=v.w;
        v = *(const float4*)(p + NN + WW);     d1[0]=v.x; d1[1]=v.y; d1[2]=v.z; d1[3]=v.w;
        v = *(const float4*)(p + 2*NN + WW);   d2[0]=v.x; d2[1]=v.y; d2[2]=v.z; d2[3]=v.w;
    } else {
        #pragma unroll
        for (int j = 0; j < 4; ++j) { d0[j] = 0.f; d1[j] = 0.f; d2[j] = 0.f; }
    }
    #pragma unroll
    for (int j = 0; j < 4; ++j) {
        float tw = 0.f;
        if (w0 + j < WW - 1)
            tw += (fabsf(c0[j]-c0[j+1]) + fabsf(c1[j]-c1[j+1]) + fabsf(c2[j]-c2[j+1])) / 3.0f;
        if (haveD)
            tw += (fabsf(c0[j]-d0[j]) + fabsf(c1[j]-d1[j]) + fabsf(c2[j]-d2[j])) / 3.0f;
        out[j] = tw * 0.5f;
    }
}

__global__ __launch_bounds__(256) void tw_sum_kernel(const float* __restrict__ img,
                                                     double* __restrict__ sum_part,
                                                     float* __restrict__ tw_out) {
    size_t g0 = ((size_t)blockIdx.x * 256 + threadIdx.x) * 4;
    float tw[4]; tw4(img, g0, tw);
    *(float4*)(tw_out + g0) = make_float4(tw[0], tw[1], tw[2], tw[3]);
    double acc = (double)((tw[0] + tw[1]) + (tw[2] + tw[3]));
    int lane = threadIdx.x & 63, wid = threadIdx.x >> 6;
    for (int o = 32; o > 0; o >>= 1) acc += __shfl_down(acc, o);
    __shared__ double sd[4];
    if (lane == 0) sd[wid] = acc;
    __syncthreads();
    if (threadIdx.x == 0) atomicAdd(&sum_part[blockIdx.x & 63], sd[0]+sd[1]+sd[2]+sd[3]);
}

__global__ __launch_bounds__(256) void mask_kernel(const float* __restrict__ tw_in,
                                                   const double* __restrict__ sum_part,
                                                   unsigned int* __restrict__ mask,
                                                   int* __restrict__ counts) {
    __shared__ float s_mean;
    __shared__ unsigned int wds[32];
    __shared__ int sv[4];
    int t = threadIdx.x;
    if (t == 0) {
        double s = 0.0;
        for (int i = 0; i < 64; ++i) s += sum_part[i];
        s_mean = (float)(s / (double)BN);
    }
    if (t < 32) wds[t] = 0;
    __syncthreads();
    float mean = s_mean;
    size_t g0 = ((size_t)blockIdx.x * 256 + t) * 4;
    float4 tw = *(const float4*)(tw_in + g0);
    unsigned int nib = (tw.x < mean ? 1u : 0u) | (tw.y < mean ? 2u : 0u)
                     | (tw.z < mean ? 4u : 0u) | (tw.w < mean ? 8u : 0u);
    atomicOr(&wds[t >> 3], nib << ((t & 7) * 4));
    int cv = 4 - __popc(nib);
    int lane = t & 63, wid = t >> 6;
    for (int o = 32; o > 0; o >>= 1) cv += __shfl_down(cv, o);
    if (lane == 0) sv[wid] = cv;
    __syncthreads();
    if (t < 32) mask[(size_t)blockIdx.x * 32 + t] = wds[t];
    if (t == 0) atomicAdd(&counts[blockIdx.x >> 3], sv[0]+sv[1]+sv[2]+sv[3]);
}

// 16 waves, one per batch row; scan 64 chunk counts -> exclusive offsets + nval
__global__ void scan_kernel(int* __restrict__ counts, int* __restrict__ nval) {
    int lane = threadIdx.x & 63;
    int row = threadIdx.x >> 6;
    int v = counts[row * 64 + lane];
    int incl = v;
    for (int o = 1; o < 64; o <<= 1) {
        int n = __shfl_up(incl, o);
        if (lane >= o) incl += n;
    }
    counts[row * 64 + lane] = incl - v;   // exclusive
    if (lane == 63) nval[row] = incl;
}

// Lane-parallel compaction: val_list[rank] = (gt[pos], pred[pos]).
__global__ __launch_bounds__(256) void scatter_kernel(const unsigned int* __restrict__ mask,
                                                      const int* __restrict__ offsets,
                                                      const float* __restrict__ gt,
                                                      const float* __restrict__ pred,
                                                      float2* __restrict__ val) {
    int cglob = blockIdx.x;        // 0..1023 (chunk of 8192 px)
    int b  = cglob >> 6;
    int t = threadIdx.x;
    __shared__ unsigned int svb[256];   // valid-bit words of this chunk
    __shared__ int swoff[256];          // word-level exclusive offsets in chunk
    __shared__ int wsum[4];
    unsigned int vb = ~mask[(size_t)cglob * 256 + t];
    svb[t] = vb;
    int cnt = __popc(vb);
    int lane = t & 63, wid = t >> 6;
    int incl = cnt;
    for (int o = 1; o < 64; o <<= 1) {
        int n = __shfl_up(incl, o);
        if (lane >= o) incl += n;
    }
    if (lane == 63) wsum[wid] = incl;
    __syncthreads();
    int woff = 0;
    for (int i = 0; i < wid; i++) woff += wsum[i];
    swoff[t] = woff + incl - cnt;
    __syncthreads();
    size_t rowb = (size_t)b << 19;
    int chunkbase = offsets[cglob];
    size_t gbase = rowb + (size_t)(cglob & 63) * 8192;
    int bit = t & 31;
    unsigned int below = (bit == 0) ? 0u : ((1u << bit) - 1u);
    #pragma unroll 4
    for (int i = 0; i < 32; ++i) {
        int e = i * 256 + t;                 // lane-contiguous element order
        unsigned int bits = svb[i * 8 + (t >> 5)];
        if ((bits >> bit) & 1u) {
            int rank = chunkbase + swoff[i * 8 + (t >> 5)] + __popc(bits & below);
            size_t src = gbase + e;
            val[rowb + rank] = make_float2(gt[src], pred[src]);
        }
    }
}

__global__ __launch_bounds__(256) void loss_kernel(const float* __restrict__ pred,
                                                   const float* __restrict__ gt,
                                                   const float* __restrict__ ur,
                                                   const unsigned int* __restrict__ mask,
                                                   const float2* __restrict__ val,
                                                   const int* __restrict__ nv_arr,
                                                   double* __restrict__ acc_ls,
                                                   double* __restrict__ acc_ss,
                                                   unsigned int* __restrict__ cnt_nz,
                                                   unsigned int* __restrict__ cnt_zz) {
    int n = blockIdx.x * 256 + threadIdx.x;   // pixel index within a row, grid=2048
    double ls = 0.0, ss = 0.0;
    unsigned int cnz = 0, czz = 0;
    #pragma unroll
    for (int b = 0; b < BB; ++b) {
        size_t g = ((size_t)b << 19) + (size_t)n;
        if ((mask[g >> 5] >> (n & 31)) & 1u) {     // invalid pixel
            int nv = nv_arr[b];
            float u_r = ur[g];
            int u = min((int)(u_r * (float)nv), nv - 1);
            float2 v = val[((size_t)b << 19) + (size_t)u];
            float gc = gt[g], pc = pred[g];
            float d = pc - v.y;
            float r1 = gc / v.x, r2 = v.x / gc;
            if (r1 >= 1.02f)      { ls += (double)log1pf(expf(-d)); ++cnz; }
            else if (r2 > 1.02f)  { ls += (double)log1pf(expf( d)); ++cnz; }
            else                  { ss += (double)(d * d); ++czz; }
        }
    }
    int lane = threadIdx.x & 63, wid = threadIdx.x >> 6;
    __shared__ double sd[4];
    __shared__ unsigned int si[4];
    for (int o = 32; o > 0; o >>= 1) ls += __shfl_down(ls, o);
    if (lane == 0) sd[wid] = ls;
    __syncthreads();
    if (threadIdx.x == 0) atomicAdd(&acc_ls[blockIdx.x & 63], sd[0]+sd[1]+sd[2]+sd[3]);
    __syncthreads();
    for (int o = 32; o > 0; o >>= 1) ss += __shfl_down(ss, o);
    if (lane == 0) sd[wid] = ss;
    __syncthreads();
    if (threadIdx.x == 0) atomicAdd(&acc_ss[blockIdx.x & 63], sd[0]+sd[1]+sd[2]+sd[3]);
    __syncthreads();
    for (int o = 32; o > 0; o >>= 1) cnz += __shfl_down(cnz, o);
    if (lane == 0) si[wid] = cnz;
    __syncthreads();
    if (threadIdx.x == 0) atomicAdd(&cnt_nz[blockIdx.x & 63], si[0]+si[1]+si[2]+si[3]);
    __syncthreads();
    for (int o = 32; o > 0; o >>= 1) czz += __shfl_down(czz, o);
    if (lane == 0) si[wid] = czz;
    __syncthreads();
    if (threadIdx.x == 0) atomicAdd(&cnt_zz[blockIdx.x & 63], si[0]+si[1]+si[2]+si[3]);
}

__global__ void finalize_kernel(const double* __restrict__ acc_ls,
                                const double* __restrict__ acc_ss,
                                const unsigned int* __restrict__ cnt_nz,
                                const unsigned int* __restrict__ cnt_zz,
                                float* __restrict__ out) {
    int t = threadIdx.x;   // 64 threads
    double l = acc_ls[t], s2 = acc_ss[t];
    unsigned int a = cnt_nz[t], c = cnt_zz[t];
    for (int o = 32; o > 0; o >>= 1) {
        l  += __shfl_down(l, o);
        s2 += __shfl_down(s2, o);
        a  += __shfl_down(a, o);
        c  += __shfl_down(c, o);
    }
    if (t == 0) out[0] = (float)(l / (double)a + s2 / (double)c);
}

extern "C" void kernel_launch(void* const* d_in, const int* in_sizes, int n_in,
                              void* d_out, int out_size, void* d_ws, size_t ws_size,
                              hipStream_t stream) {
    const float* pred = (const float*)d_in[0];
    const float* gt   = (const float*)d_in[1];
    const float* img  = (const float*)d_in[2];
    const float* ur   = (const float*)d_in[3];
    float* out = (float*)d_out;

    char* ws = (char*)d_ws;
    double*       sum_part = (double*)(ws + 0);
    double*       acc_ls   = (double*)(ws + 512);
    double*       acc_ss   = (double*)(ws + 1024);
    unsigned int* cnt_nz   = (unsigned int*)(ws + 1536);
    unsigned int* cnt_zz   = (unsigned int*)(ws + 1792);
    int*          nval     = (int*)(ws + 2048);
    int*          counts   = (int*)(ws + 4096);
    unsigned int* mask     = (unsigned int*)(ws + 8192);
    float2*       val      = (float2*)(ws + (1 << 21));
    float*        tw       = (float*)(ws + (1 << 21));   // aliases val (pre-scatter)

    hipMemsetAsync(ws, 0, 8192, stream);
    tw_sum_kernel <<<8192, 256, 0, stream>>>(img, sum_part, tw);
    mask_kernel   <<<8192, 256, 0, stream>>>(tw, sum_part, mask, counts);
    scan_kernel   <<<1, 1024, 0, stream>>>(counts, nval);
    scatter_kernel<<<1024, 256, 0, stream>>>(mask, counts, gt, pred, val);
    loss_kernel   <<<2048, 256, 0, stream>>>(pred, gt, ur, mask, val, nval,
                                             acc_ls, acc_ss, cnt_nz, cnt_zz);
    finalize_kernel<<<1, 64, 0, stream>>>(acc_ls, acc_ss, cnt_nz, cnt_zz, out);
}

// Round 4
// 157.670 us; speedup vs baseline: 3.5368x; 1.0085x over previous
//
#include <hip/hip_runtime.h>
#include <hip/hip_bf16.h>
#include <math.h>

#define BB 16
#define CC 3
#define HH 512
#define WW 1024
#define NN (HH * WW)          // 524288 = 2^19
#define BN ((size_t)BB * NN)  // 8388608 = 2^23

typedef __attribute__((ext_vector_type(4))) _Float16 half4;

// ws layout (bytes):
//   0    : double sum_part[64]
//   512  : double acc_ls[64]
//   1024 : double acc_ss[64]
//   1536 : uint   cnt_nz[64]
//   1792 : uint   cnt_zz[64]
//   2048 : int    nval[16]
//   4096 : int    counts[1024]
//   8192 : uint   mask[BN/32]       invalid bits, 1 MB
//   2MB  : float2 val_list[BN]      (gt_val, pred_val) compacted, 67 MB
//          region doubles as tw[BN] (_Float16, 16.8 MB) before scatter.

__device__ __forceinline__ void tw4(const float* __restrict__ img, size_t g0, float out[4]) {
    int w0 = (int)(g0 & (WW - 1));
    int h  = (int)((g0 >> 10) & (HH - 1));
    int b  = (int)(g0 >> 19);
    const float* p = img + (size_t)b * CC * NN + (size_t)h * WW + w0;
    float c0[5], c1[5], c2[5], d0[4], d1[4], d2[4];
    float4 v;
    v = *(const float4*)p;            c0[0]=v.x; c0[1]=v.y; c0[2]=v.z; c0[3]=v.w;
    v = *(const float4*)(p + NN);     c1[0]=v.x; c1[1]=v.y; c1[2]=v.z; c1[3]=v.w;
    v = *(const float4*)(p + 2*NN);   c2[0]=v.x; c2[1]=v.y; c2[2]=v.z; c2[3]=v.w;
    bool haveR = (w0 < WW - 4);
    c0[4] = haveR ? p[4]        : 0.f;
    c1[4] = haveR ? p[NN + 4]   : 0.f;
    c2[4] = haveR ? p[2*NN + 4] : 0.f;
    bool haveD = (h < HH - 1);
    if (haveD) {
        v = *(const float4*)(p + WW);          d0[0]=v.x; d0[1]=v.y; d0[2]=v.z; d0[3]=v.w;
        v = *(const float4*)(p + NN + WW);     d1[0]=v.x; d1[1]=v.y; d1[2]=v.z; d1[3]=v.w;
        v = *(const float4*)(p + 2*NN + WW);   d2[0]=v.x; d2[1]=v.y; d2[2]=v.z; d2[3]=v.w;
    } else {
        #pragma unroll
        for (int j = 0; j < 4; ++j) { d0[j] = 0.f; d1[j] = 0.f; d2[j] = 0.f; }
    }
    #pragma unroll
    for (int j = 0; j < 4; ++j) {
        float tw = 0.f;
        if (w0 + j < WW - 1)
            tw += (fabsf(c0[j]-c0[j+1]) + fabsf(c1[j]-c1[j+1]) + fabsf(c2[j]-c2[j+1])) / 3.0f;
        if (haveD)
            tw += (fabsf(c0[j]-d0[j]) + fabsf(c1[j]-d1[j]) + fabsf(c2[j]-d2[j])) / 3.0f;
        out[j] = tw * 0.5f;
    }
}

__global__ __launch_bounds__(256) void tw_sum_kernel(const float* __restrict__ img,
                                                     double* __restrict__ sum_part,
                                                     _Float16* __restrict__ tw_out) {
    size_t g0 = ((size_t)blockIdx.x * 256 + threadIdx.x) * 4;
    float tw[4]; tw4(img, g0, tw);
    half4 hv; hv.x = (_Float16)tw[0]; hv.y = (_Float16)tw[1];
    hv.z = (_Float16)tw[2]; hv.w = (_Float16)tw[3];
    *(half4*)(tw_out + g0) = hv;
    double acc = (double)((tw[0] + tw[1]) + (tw[2] + tw[3]));
    int lane = threadIdx.x & 63, wid = threadIdx.x >> 6;
    for (int o = 32; o > 0; o >>= 1) acc += __shfl_down(acc, o);
    __shared__ double sd[4];
    if (lane == 0) sd[wid] = acc;
    __syncthreads();
    if (threadIdx.x == 0) atomicAdd(&sum_part[blockIdx.x & 63], sd[0]+sd[1]+sd[2]+sd[3]);
}

__global__ __launch_bounds__(256) void mask_kernel(const _Float16* __restrict__ tw_in,
                                                   const double* __restrict__ sum_part,
                                                   unsigned int* __restrict__ mask,
                                                   int* __restrict__ counts) {
    __shared__ float s_mean;
    __shared__ unsigned int wds[32];
    __shared__ int sv[4];
    int t = threadIdx.x;
    if (t == 0) {
        double s = 0.0;
        for (int i = 0; i < 64; ++i) s += sum_part[i];
        s_mean = (float)(s / (double)BN);
    }
    if (t < 32) wds[t] = 0;
    __syncthreads();
    float mean = s_mean;
    size_t g0 = ((size_t)blockIdx.x * 256 + t) * 4;
    half4 hv = *(const half4*)(tw_in + g0);
    unsigned int nib = ((float)hv.x < mean ? 1u : 0u) | ((float)hv.y < mean ? 2u : 0u)
                     | ((float)hv.z < mean ? 4u : 0u) | ((float)hv.w < mean ? 8u : 0u);
    atomicOr(&wds[t >> 3], nib << ((t & 7) * 4));
    int cv = 4 - __popc(nib);
    int lane = t & 63, wid = t >> 6;
    for (int o = 32; o > 0; o >>= 1) cv += __shfl_down(cv, o);
    if (lane == 0) sv[wid] = cv;
    __syncthreads();
    if (t < 32) mask[(size_t)blockIdx.x * 32 + t] = wds[t];
    if (t == 0) atomicAdd(&counts[blockIdx.x >> 3], sv[0]+sv[1]+sv[2]+sv[3]);
}

__global__ void scan_kernel(int* __restrict__ counts, int* __restrict__ nval) {
    int lane = threadIdx.x & 63;
    int row = threadIdx.x >> 6;
    int v = counts[row * 64 + lane];
    int incl = v;
    for (int o = 1; o < 64; o <<= 1) {
        int n = __shfl_up(incl, o);
        if (lane >= o) incl += n;
    }
    counts[row * 64 + lane] = incl - v;
    if (lane == 63) nval[row] = incl;
}

__global__ __launch_bounds__(256) void scatter_kernel(const unsigned int* __restrict__ mask,
                                                      const int* __restrict__ offsets,
                                                      const float* __restrict__ gt,
                                                      const float* __restrict__ pred,
                                                      float2* __restrict__ val) {
    int cglob = blockIdx.x;        // 0..1023 (chunk of 8192 px)
    int b  = cglob >> 6;
    int t = threadIdx.x;
    __shared__ unsigned int svb[256];
    __shared__ int swoff[256];
    __shared__ int wsum[4];
    unsigned int vb = ~mask[(size_t)cglob * 256 + t];
    svb[t] = vb;
    int cnt = __popc(vb);
    int lane = t & 63, wid = t >> 6;
    int incl = cnt;
    for (int o = 1; o < 64; o <<= 1) {
        int n = __shfl_up(incl, o);
        if (lane >= o) incl += n;
    }
    if (lane == 63) wsum[wid] = incl;
    __syncthreads();
    int woff = 0;
    for (int i = 0; i < wid; i++) woff += wsum[i];
    swoff[t] = woff + incl - cnt;
    __syncthreads();
    size_t rowb = (size_t)b << 19;
    int chunkbase = offsets[cglob];
    size_t gbase = rowb + (size_t)(cglob & 63) * 8192;
    int bit = t & 31;
    unsigned int below = (bit == 0) ? 0u : ((1u << bit) - 1u);
    #pragma unroll 4
    for (int i = 0; i < 32; ++i) {
        int e = i * 256 + t;
        unsigned int bits = svb[i * 8 + (t >> 5)];
        if ((bits >> bit) & 1u) {
            int rank = chunkbase + swoff[i * 8 + (t >> 5)] + __popc(bits & below);
            size_t src = gbase + e;
            val[rowb + rank] = make_float2(gt[src], pred[src]);
        }
    }
}

__device__ __forceinline__ float fget(const float4& v, int k) {
    switch (k) { case 0: return v.x; case 1: return v.y; case 2: return v.z; default: return v.w; }
}

// One row per block: bid>>7 = b; thread owns 16 consecutive pixels (64 B/array).
__global__ __launch_bounds__(256) void loss_kernel(const float* __restrict__ pred,
                                                   const float* __restrict__ gt,
                                                   const float* __restrict__ ur,
                                                   const unsigned int* __restrict__ mask,
                                                   const float2* __restrict__ val,
                                                   const int* __restrict__ nv_arr,
                                                   double* __restrict__ acc_ls,
                                                   double* __restrict__ acc_ss,
                                                   unsigned int* __restrict__ cnt_nz,
                                                   unsigned int* __restrict__ cnt_zz) {
    int t = threadIdx.x;
    int bid = blockIdx.x;                       // 2048 blocks
    int b = bid >> 7;                           // 128 blocks per row
    size_t rowb = (size_t)b << 19;
    int n0 = ((bid & 127) << 12) + t * 16;      // within-row pixel base
    size_t g0 = rowb + (size_t)n0;
    unsigned int bits = (mask[g0 >> 5] >> ((t & 1) << 4)) & 0xFFFFu;
    int nv = nv_arr[b];
    float fnv = (float)nv;
    float4 U[4], G[4], P[4];
    const float4* up = (const float4*)(ur + g0);
    const float4* gp = (const float4*)(gt + g0);
    const float4* pp = (const float4*)(pred + g0);
    #pragma unroll
    for (int i = 0; i < 4; ++i) { U[i] = up[i]; G[i] = gp[i]; P[i] = pp[i]; }
    float ls = 0.f, ss = 0.f;
    int cnz = 0, czz = 0;
    #pragma unroll
    for (int j = 0; j < 16; ++j) {
        if ((bits >> j) & 1u) {                 // invalid pixel
            float urv = fget(U[j >> 2], j & 3);
            int u = min((int)(urv * fnv), nv - 1);
            float2 v = val[rowb + (size_t)u];
            float gc = fget(G[j >> 2], j & 3);
            float pc = fget(P[j >> 2], j & 3);
            float d = pc - v.y;
            if (gc >= 1.02f * v.x)      { ls += __logf(1.f + __expf(-d)); ++cnz; }
            else if (v.x > 1.02f * gc)  { ls += __logf(1.f + __expf( d)); ++cnz; }
            else                        { ss += d * d; ++czz; }
        }
    }
    int lane = t & 63, wid = t >> 6;
    __shared__ double sd[4];
    __shared__ unsigned int si[4];
    double lsd = (double)ls, ssd = (double)ss;
    for (int o = 32; o > 0; o >>= 1) lsd += __shfl_down(lsd, o);
    if (lane == 0) sd[wid] = lsd;
    __syncthreads();
    if (t == 0) atomicAdd(&acc_ls[bid & 63], sd[0]+sd[1]+sd[2]+sd[3]);
    __syncthreads();
    for (int o = 32; o > 0; o >>= 1) ssd += __shfl_down(ssd, o);
    if (lane == 0) sd[wid] = ssd;
    __syncthreads();
    if (t == 0) atomicAdd(&acc_ss[bid & 63], sd[0]+sd[1]+sd[2]+sd[3]);
    __syncthreads();
    for (int o = 32; o > 0; o >>= 1) cnz += __shfl_down(cnz, o);
    if (lane == 0) si[wid] = (unsigned int)cnz;
    __syncthreads();
    if (t == 0) atomicAdd(&cnt_nz[bid & 63], si[0]+si[1]+si[2]+si[3]);
    __syncthreads();
    for (int o = 32; o > 0; o >>= 1) czz += __shfl_down(czz, o);
    if (lane == 0) si[wid] = (unsigned int)czz;
    __syncthreads();
    if (t == 0) atomicAdd(&cnt_zz[bid & 63], si[0]+si[1]+si[2]+si[3]);
}

__global__ void finalize_kernel(const double* __restrict__ acc_ls,
                                const double* __restrict__ acc_ss,
                                const unsigned int* __restrict__ cnt_nz,
                                const unsigned int* __restrict__ cnt_zz,
                                float* __restrict__ out) {
    int t = threadIdx.x;
    double l = acc_ls[t], s2 = acc_ss[t];
    unsigned int a = cnt_nz[t], c = cnt_zz[t];
    for (int o = 32; o > 0; o >>= 1) {
        l  += __shfl_down(l, o);
        s2 += __shfl_down(s2, o);
        a  += __shfl_down(a, o);
        c  += __shfl_down(c, o);
    }
    if (t == 0) out[0] = (float)(l / (double)a + s2 / (double)c);
}

extern "C" void kernel_launch(void* const* d_in, const int* in_sizes, int n_in,
                              void* d_out, int out_size, void* d_ws, size_t ws_size,
                              hipStream_t stream) {
    const float* pred = (const float*)d_in[0];
    const float* gt   = (const float*)d_in[1];
    const float* img  = (const float*)d_in[2];
    const float* ur   = (const float*)d_in[3];
    float* out = (float*)d_out;

    char* ws = (char*)d_ws;
    double*       sum_part = (double*)(ws + 0);
    double*       acc_ls   = (double*)(ws + 512);
    double*       acc_ss   = (double*)(ws + 1024);
    unsigned int* cnt_nz   = (unsigned int*)(ws + 1536);
    unsigned int* cnt_zz   = (unsigned int*)(ws + 1792);
    int*          nval     = (int*)(ws + 2048);
    int*          counts   = (int*)(ws + 4096);
    unsigned int* mask     = (unsigned int*)(ws + 8192);
    float2*       val      = (float2*)(ws + (1 << 21));
    _Float16*     tw       = (_Float16*)(ws + (1 << 21));   // aliases val (pre-scatter)

    hipMemsetAsync(ws, 0, 8192, stream);
    tw_sum_kernel <<<8192, 256, 0, stream>>>(img, sum_part, tw);
    mask_kernel   <<<8192, 256, 0, stream>>>(tw, sum_part, mask, counts);
    scan_kernel   <<<1, 1024, 0, stream>>>(counts, nval);
    scatter_kernel<<<1024, 256, 0, stream>>>(mask, counts, gt, pred, val);
    loss_kernel   <<<2048, 256, 0, stream>>>(pred, gt, ur, mask, val, nval,
                                             acc_ls, acc_ss, cnt_nz, cnt_zz);
    finalize_kernel<<<1, 64, 0, stream>>>(acc_ls, acc_ss, cnt_nz, cnt_zz, out);
}

// Round 6
// 126.085 us; speedup vs baseline: 4.4228x; 1.2505x over previous
//
#include <hip/hip_runtime.h>
#include <hip/hip_bf16.h>
#include <math.h>

#define BB 16
#define CC 3
#define HH 512
#define WW 1024
#define NN (HH * WW)          // 524288 = 2^19
#define BN ((size_t)BB * NN)  // 8388608 = 2^23

typedef __attribute__((ext_vector_type(4))) _Float16 half4;
typedef __attribute__((ext_vector_type(2))) _Float16 h2;
typedef __attribute__((ext_vector_type(4))) float f4;

// ws layout (bytes):
//   0    : double sum_part[64]
//   512  : double acc_ls[64]
//   1024 : double acc_ss[64]
//   1536 : uint   cnt_nz[64]
//   1792 : uint   cnt_zz[64]
//   2048 : int    nval[16]
//   4096 : int    counts[1024]
//   8192 : uint   mask[BN/32]       invalid bits, 1 MB
//   2MB  : h2     val_list[BN]      (gt_val, pred_val) compacted, 33.5 MB
//          region doubles as tw[BN] (_Float16, 16.8 MB) before scatter.

__device__ __forceinline__ void tw4(const float* __restrict__ img, size_t g0, float out[4]) {
    int w0 = (int)(g0 & (WW - 1));
    int h  = (int)((g0 >> 10) & (HH - 1));
    int b  = (int)(g0 >> 19);
    const float* p = img + (size_t)b * CC * NN + (size_t)h * WW + w0;
    float c0[5], c1[5], c2[5], d0[4], d1[4], d2[4];
    f4 v;
    v = *(const f4*)p;            c0[0]=v.x; c0[1]=v.y; c0[2]=v.z; c0[3]=v.w;
    v = *(const f4*)(p + NN);     c1[0]=v.x; c1[1]=v.y; c1[2]=v.z; c1[3]=v.w;
    v = *(const f4*)(p + 2*NN);   c2[0]=v.x; c2[1]=v.y; c2[2]=v.z; c2[3]=v.w;
    bool haveR = (w0 < WW - 4);
    c0[4] = haveR ? p[4]        : 0.f;
    c1[4] = haveR ? p[NN + 4]   : 0.f;
    c2[4] = haveR ? p[2*NN + 4] : 0.f;
    bool haveD = (h < HH - 1);
    if (haveD) {
        v = *(const f4*)(p + WW);          d0[0]=v.x; d0[1]=v.y; d0[2]=v.z; d0[3]=v.w;
        v = *(const f4*)(p + NN + WW);     d1[0]=v.x; d1[1]=v.y; d1[2]=v.z; d1[3]=v.w;
        v = *(const f4*)(p + 2*NN + WW);   d2[0]=v.x; d2[1]=v.y; d2[2]=v.z; d2[3]=v.w;
    } else {
        #pragma unroll
        for (int j = 0; j < 4; ++j) { d0[j] = 0.f; d1[j] = 0.f; d2[j] = 0.f; }
    }
    #pragma unroll
    for (int j = 0; j < 4; ++j) {
        float tw = 0.f;
        if (w0 + j < WW - 1)
            tw += (fabsf(c0[j]-c0[j+1]) + fabsf(c1[j]-c1[j+1]) + fabsf(c2[j]-c2[j+1])) / 3.0f;
        if (haveD)
            tw += (fabsf(c0[j]-d0[j]) + fabsf(c1[j]-d1[j]) + fabsf(c2[j]-d2[j])) / 3.0f;
        out[j] = tw * 0.5f;
    }
}

__global__ __launch_bounds__(256) void tw_sum_kernel(const float* __restrict__ img,
                                                     double* __restrict__ sum_part,
                                                     _Float16* __restrict__ tw_out) {
    size_t g0 = ((size_t)blockIdx.x * 256 + threadIdx.x) * 4;
    float tw[4]; tw4(img, g0, tw);
    half4 hv; hv.x = (_Float16)tw[0]; hv.y = (_Float16)tw[1];
    hv.z = (_Float16)tw[2]; hv.w = (_Float16)tw[3];
    *(half4*)(tw_out + g0) = hv;
    double acc = (double)((tw[0] + tw[1]) + (tw[2] + tw[3]));
    int lane = threadIdx.x & 63, wid = threadIdx.x >> 6;
    for (int o = 32; o > 0; o >>= 1) acc += __shfl_down(acc, o);
    __shared__ double sd[4];
    if (lane == 0) sd[wid] = acc;
    __syncthreads();
    if (threadIdx.x == 0) atomicAdd(&sum_part[blockIdx.x & 63], sd[0]+sd[1]+sd[2]+sd[3]);
}

__global__ __launch_bounds__(256) void mask_kernel(const _Float16* __restrict__ tw_in,
                                                   const double* __restrict__ sum_part,
                                                   unsigned int* __restrict__ mask,
                                                   int* __restrict__ counts) {
    __shared__ float s_mean;
    __shared__ unsigned int wds[32];
    __shared__ int sv[4];
    int t = threadIdx.x;
    if (t == 0) {
        double s = 0.0;
        for (int i = 0; i < 64; ++i) s += sum_part[i];
        s_mean = (float)(s / (double)BN);
    }
    if (t < 32) wds[t] = 0;
    __syncthreads();
    float mean = s_mean;
    size_t g0 = ((size_t)blockIdx.x * 256 + t) * 4;
    half4 hv = *(const half4*)(tw_in + g0);
    unsigned int nib = ((float)hv.x < mean ? 1u : 0u) | ((float)hv.y < mean ? 2u : 0u)
                     | ((float)hv.z < mean ? 4u : 0u) | ((float)hv.w < mean ? 8u : 0u);
    atomicOr(&wds[t >> 3], nib << ((t & 7) * 4));
    int cv = 4 - __popc(nib);
    int lane = t & 63, wid = t >> 6;
    for (int o = 32; o > 0; o >>= 1) cv += __shfl_down(cv, o);
    if (lane == 0) sv[wid] = cv;
    __syncthreads();
    if (t < 32) mask[(size_t)blockIdx.x * 32 + t] = wds[t];
    if (t == 0) atomicAdd(&counts[blockIdx.x >> 3], sv[0]+sv[1]+sv[2]+sv[3]);
}

__global__ void scan_kernel(int* __restrict__ counts, int* __restrict__ nval) {
    int lane = threadIdx.x & 63;
    int row = threadIdx.x >> 6;
    int v = counts[row * 64 + lane];
    int incl = v;
    for (int o = 1; o < 64; o <<= 1) {
        int n = __shfl_up(incl, o);
        if (lane >= o) incl += n;
    }
    counts[row * 64 + lane] = incl - v;
    if (lane == 63) nval[row] = incl;
}

__global__ __launch_bounds__(256) void scatter_kernel(const unsigned int* __restrict__ mask,
                                                      const int* __restrict__ offsets,
                                                      const float* __restrict__ gt,
                                                      const float* __restrict__ pred,
                                                      h2* __restrict__ val) {
    int cglob = blockIdx.x;        // 0..1023 (chunk of 8192 px)
    int b  = cglob >> 6;
    int t = threadIdx.x;
    __shared__ unsigned int svb[256];
    __shared__ int swoff[256];
    __shared__ int wsum[4];
    unsigned int vb = ~mask[(size_t)cglob * 256 + t];
    svb[t] = vb;
    int cnt = __popc(vb);
    int lane = t & 63, wid = t >> 6;
    int incl = cnt;
    for (int o = 1; o < 64; o <<= 1) {
        int n = __shfl_up(incl, o);
        if (lane >= o) incl += n;
    }
    if (lane == 63) wsum[wid] = incl;
    __syncthreads();
    int woff = 0;
    for (int i = 0; i < wid; i++) woff += wsum[i];
    swoff[t] = woff + incl - cnt;
    __syncthreads();
    size_t rowb = (size_t)b << 19;
    int chunkbase = offsets[cglob];
    size_t gbase = rowb + (size_t)(cglob & 63) * 8192;
    int bit = t & 31;
    unsigned int below = (bit == 0) ? 0u : ((1u << bit) - 1u);
    #pragma unroll 4
    for (int i = 0; i < 32; ++i) {
        int e = i * 256 + t;
        unsigned int bits = svb[i * 8 + (t >> 5)];
        if ((bits >> bit) & 1u) {
            int rank = chunkbase + swoff[i * 8 + (t >> 5)] + __popc(bits & below);
            size_t src = gbase + e;
            h2 o; o.x = (_Float16)gt[src]; o.y = (_Float16)pred[src];
            val[rowb + rank] = o;
        }
    }
}

__device__ __forceinline__ float fget(const f4& v, int k) {
    switch (k) { case 0: return v.x; case 1: return v.y; case 2: return v.z; default: return v.w; }
}

// One row per block, XCD-clustered: rows {2x,2x+1} -> XCD x (blockIdx%8 heuristic).
__global__ __launch_bounds__(256) void loss_kernel(const float* __restrict__ pred,
                                                   const float* __restrict__ gt,
                                                   const float* __restrict__ ur,
                                                   const unsigned int* __restrict__ mask,
                                                   const h2* __restrict__ val,
                                                   const int* __restrict__ nv_arr,
                                                   double* __restrict__ acc_ls,
                                                   double* __restrict__ acc_ss,
                                                   unsigned int* __restrict__ cnt_nz,
                                                   unsigned int* __restrict__ cnt_zz) {
    int t = threadIdx.x;
    int bid = blockIdx.x;                       // 2048 blocks
    int b = ((bid & 7) << 1) | ((bid >> 3) & 1);
    int chunk = bid >> 4;                       // 128 chunks per row
    size_t rowb = (size_t)b << 19;
    int n0 = (chunk << 12) + t * 16;
    size_t g0 = rowb + (size_t)n0;
    unsigned int bits =
        (__builtin_nontemporal_load(&mask[g0 >> 5]) >> ((t & 1) << 4)) & 0xFFFFu;
    int nv = nv_arr[b];
    float fnv = (float)nv;
    f4 U[4], G[4], P[4];
    const f4* up = (const f4*)(ur + g0);
    const f4* gp = (const f4*)(gt + g0);
    const f4* pp = (const f4*)(pred + g0);
    #pragma unroll
    for (int i = 0; i < 4; ++i) {
        U[i] = __builtin_nontemporal_load(up + i);
        G[i] = __builtin_nontemporal_load(gp + i);
        P[i] = __builtin_nontemporal_load(pp + i);
    }
    float ls = 0.f, ss = 0.f;
    int cnz = 0, czz = 0;
    #pragma unroll
    for (int j = 0; j < 16; ++j) {
        if ((bits >> j) & 1u) {                 // invalid pixel
            float urv = fget(U[j >> 2], j & 3);
            int u = min((int)(urv * fnv), nv - 1);
            h2 v = val[rowb + (size_t)u];
            float vx = (float)v.x, vy = (float)v.y;
            float gc = fget(G[j >> 2], j & 3);
            float pc = fget(P[j >> 2], j & 3);
            float d = pc - vy;
            if (gc >= 1.02f * vx)      { ls += __logf(1.f + __expf(-d)); ++cnz; }
            else if (vx > 1.02f * gc)  { ls += __logf(1.f + __expf( d)); ++cnz; }
            else                       { ss += d * d; ++czz; }
        }
    }
    int lane = t & 63, wid = t >> 6;
    __shared__ double sd[4];
    __shared__ unsigned int si[4];
    double lsd = (double)ls, ssd = (double)ss;
    for (int o = 32; o > 0; o >>= 1) lsd += __shfl_down(lsd, o);
    if (lane == 0) sd[wid] = lsd;
    __syncthreads();
    if (t == 0) atomicAdd(&acc_ls[bid & 63], sd[0]+sd[1]+sd[2]+sd[3]);
    __syncthreads();
    for (int o = 32; o > 0; o >>= 1) ssd += __shfl_down(ssd, o);
    if (lane == 0) sd[wid] = ssd;
    __syncthreads();
    if (t == 0) atomicAdd(&acc_ss[bid & 63], sd[0]+sd[1]+sd[2]+sd[3]);
    __syncthreads();
    for (int o = 32; o > 0; o >>= 1) cnz += __shfl_down(cnz, o);
    if (lane == 0) si[wid] = (unsigned int)cnz;
    __syncthreads();
    if (t == 0) atomicAdd(&cnt_nz[bid & 63], si[0]+si[1]+si[2]+si[3]);
    __syncthreads();
    for (int o = 32; o > 0; o >>= 1) czz += __shfl_down(czz, o);
    if (lane == 0) si[wid] = (unsigned int)czz;
    __syncthreads();
    if (t == 0) atomicAdd(&cnt_zz[bid & 63], si[0]+si[1]+si[2]+si[3]);
}

__global__ void finalize_kernel(const double* __restrict__ acc_ls,
                                const double* __restrict__ acc_ss,
                                const unsigned int* __restrict__ cnt_nz,
                                const unsigned int* __restrict__ cnt_zz,
                                float* __restrict__ out) {
    int t = threadIdx.x;
    double l = acc_ls[t], s2 = acc_ss[t];
    unsigned int a = cnt_nz[t], c = cnt_zz[t];
    for (int o = 32; o > 0; o >>= 1) {
        l  += __shfl_down(l, o);
        s2 += __shfl_down(s2, o);
        a  += __shfl_down(a, o);
        c  += __shfl_down(c, o);
    }
    if (t == 0) out[0] = (float)(l / (double)a + s2 / (double)c);
}

extern "C" void kernel_launch(void* const* d_in, const int* in_sizes, int n_in,
                              void* d_out, int out_size, void* d_ws, size_t ws_size,
                              hipStream_t stream) {
    const float* pred = (const float*)d_in[0];
    const float* gt   = (const float*)d_in[1];
    const float* img  = (const float*)d_in[2];
    const float* ur   = (const float*)d_in[3];
    float* out = (float*)d_out;

    char* ws = (char*)d_ws;
    double*       sum_part = (double*)(ws + 0);
    double*       acc_ls   = (double*)(ws + 512);
    double*       acc_ss   = (double*)(ws + 1024);
    unsigned int* cnt_nz   = (unsigned int*)(ws + 1536);
    unsigned int* cnt_zz   = (unsigned int*)(ws + 1792);
    int*          nval     = (int*)(ws + 2048);
    int*          counts   = (int*)(ws + 4096);
    unsigned int* mask     = (unsigned int*)(ws + 8192);
    h2*           val      = (h2*)(ws + (1 << 21));
    _Float16*     tw       = (_Float16*)(ws + (1 << 21));   // aliases val (pre-scatter)

    (void)hipMemsetAsync(ws, 0, 8192, stream);
    tw_sum_kernel <<<8192, 256, 0, stream>>>(img, sum_part, tw);
    mask_kernel   <<<8192, 256, 0, stream>>>(tw, sum_part, mask, counts);
    scan_kernel   <<<1, 1024, 0, stream>>>(counts, nval);
    scatter_kernel<<<1024, 256, 0, stream>>>(mask, counts, gt, pred, val);
    loss_kernel   <<<2048, 256, 0, stream>>>(pred, gt, ur, mask, val, nval,
                                             acc_ls, acc_ss, cnt_nz, cnt_zz);
    finalize_kernel<<<1, 64, 0, stream>>>(acc_ls, acc_ss, cnt_nz, cnt_zz, out);
}

// Round 7
// 111.138 us; speedup vs baseline: 5.0176x; 1.1345x over previous
//
#include <hip/hip_runtime.h>
#include <hip/hip_bf16.h>
#include <math.h>

#define BB 16
#define CC 3
#define HH 512
#define WW 1024
#define NN (HH * WW)          // 524288 = 2^19
#define BN ((size_t)BB * NN)  // 8388608 = 2^23
#define RPB 4                 // rows per tw_sum block

typedef __attribute__((ext_vector_type(4))) _Float16 half4;
typedef __attribute__((ext_vector_type(2))) _Float16 h2;
typedef __attribute__((ext_vector_type(4))) float f4;

// ws layout (bytes):
//   0    : double sum_part[64]
//   512  : double acc_ls[64]
//   1024 : double acc_ss[64]
//   1536 : uint   cnt_nz[64]
//   1792 : uint   cnt_zz[64]
//   2048 : int    nval[16]
//   4096 : int    counts[1024]
//   8192 : uint   mask[BN/32]       invalid bits, 1 MB
//   2MB  : h2     val_list[BN]      (gt_val, pred_val) compacted, 33.5 MB
//          region doubles as tw[BN] (_Float16, 16.8 MB) before scatter.

// 4 rows per block, register-carried vertical neighbor: reads 5 rows, computes 4.
__global__ __launch_bounds__(256) void tw_sum_kernel(const float* __restrict__ img,
                                                     double* __restrict__ sum_part,
                                                     _Float16* __restrict__ tw_out) {
    int t = threadIdx.x;
    int bid = blockIdx.x;                  // 2048 = 16 imgs * 128 row-groups
    int b = bid >> 7;
    int h0 = (bid & 127) * RPB;
    const float* base = img + (size_t)b * CC * NN;
    int w0 = t * 4;
    bool haveR = (w0 < WW - 4);
    size_t rb = (size_t)h0 * WW + w0;
    // current row registers (3 channels, 4 px + 1 overlap)
    f4 c0 = *(const f4*)(base + rb);
    f4 c1 = *(const f4*)(base + NN + rb);
    f4 c2 = *(const f4*)(base + 2 * NN + rb);
    float e0 = haveR ? base[rb + 4] : 0.f;
    float e1 = haveR ? base[NN + rb + 4] : 0.f;
    float e2 = haveR ? base[2 * NN + rb + 4] : 0.f;
    float rowacc = 0.f;
    #pragma unroll
    for (int r = 0; r < RPB; ++r) {
        int h = h0 + r;
        bool haveD = (h < HH - 1);
        size_t db = (size_t)(h + 1) * WW + w0;
        f4 d0, d1, d2;
        float f0, f1, f2;
        if (haveD) {
            d0 = *(const f4*)(base + db);
            d1 = *(const f4*)(base + NN + db);
            d2 = *(const f4*)(base + 2 * NN + db);
            f0 = haveR ? base[db + 4] : 0.f;
            f1 = haveR ? base[NN + db + 4] : 0.f;
            f2 = haveR ? base[2 * NN + db + 4] : 0.f;
        } else {
            d0 = d1 = d2 = (f4)0.f;
            f0 = f1 = f2 = 0.f;
        }
        float a0[5] = {c0.x, c0.y, c0.z, c0.w, e0};
        float a1[5] = {c1.x, c1.y, c1.z, c1.w, e1};
        float a2[5] = {c2.x, c2.y, c2.z, c2.w, e2};
        float b0[4] = {d0.x, d0.y, d0.z, d0.w};
        float b1[4] = {d1.x, d1.y, d1.z, d1.w};
        float b2[4] = {d2.x, d2.y, d2.z, d2.w};
        float tw[4];
        #pragma unroll
        for (int j = 0; j < 4; ++j) {
            float twv = 0.f;
            if (w0 + j < WW - 1)
                twv += (fabsf(a0[j]-a0[j+1]) + fabsf(a1[j]-a1[j+1]) + fabsf(a2[j]-a2[j+1])) / 3.0f;
            if (haveD)
                twv += (fabsf(a0[j]-b0[j]) + fabsf(a1[j]-b1[j]) + fabsf(a2[j]-b2[j])) / 3.0f;
            tw[j] = twv * 0.5f;
        }
        half4 hv; hv.x = (_Float16)tw[0]; hv.y = (_Float16)tw[1];
        hv.z = (_Float16)tw[2]; hv.w = (_Float16)tw[3];
        *(half4*)(tw_out + (size_t)b * NN + (size_t)h * WW + w0) = hv;
        rowacc += (tw[0] + tw[1]) + (tw[2] + tw[3]);
        // carry down-row into current
        c0 = d0; c1 = d1; c2 = d2; e0 = f0; e1 = f1; e2 = f2;
    }
    double acc = (double)rowacc;
    int lane = t & 63, wid = t >> 6;
    for (int o = 32; o > 0; o >>= 1) acc += __shfl_down(acc, o);
    __shared__ double sd[4];
    if (lane == 0) sd[wid] = acc;
    __syncthreads();
    if (t == 0) atomicAdd(&sum_part[bid & 63], sd[0]+sd[1]+sd[2]+sd[3]);
}

__global__ __launch_bounds__(256) void mask_kernel(const _Float16* __restrict__ tw_in,
                                                   const double* __restrict__ sum_part,
                                                   unsigned int* __restrict__ mask,
                                                   int* __restrict__ counts) {
    __shared__ float s_mean;
    __shared__ unsigned int wds[32];
    __shared__ int sv[4];
    int t = threadIdx.x;
    if (t == 0) {
        double s = 0.0;
        for (int i = 0; i < 64; ++i) s += sum_part[i];
        s_mean = (float)(s / (double)BN);
    }
    if (t < 32) wds[t] = 0;
    __syncthreads();
    float mean = s_mean;
    size_t g0 = ((size_t)blockIdx.x * 256 + t) * 4;
    half4 hv = *(const half4*)(tw_in + g0);
    unsigned int nib = ((float)hv.x < mean ? 1u : 0u) | ((float)hv.y < mean ? 2u : 0u)
                     | ((float)hv.z < mean ? 4u : 0u) | ((float)hv.w < mean ? 8u : 0u);
    atomicOr(&wds[t >> 3], nib << ((t & 7) * 4));
    int cv = 4 - __popc(nib);
    int lane = t & 63, wid = t >> 6;
    for (int o = 32; o > 0; o >>= 1) cv += __shfl_down(cv, o);
    if (lane == 0) sv[wid] = cv;
    __syncthreads();
    if (t < 32) mask[(size_t)blockIdx.x * 32 + t] = wds[t];
    if (t == 0) atomicAdd(&counts[blockIdx.x >> 3], sv[0]+sv[1]+sv[2]+sv[3]);
}

__global__ void scan_kernel(int* __restrict__ counts, int* __restrict__ nval) {
    int lane = threadIdx.x & 63;
    int row = threadIdx.x >> 6;
    int v = counts[row * 64 + lane];
    int incl = v;
    for (int o = 1; o < 64; o <<= 1) {
        int n = __shfl_up(incl, o);
        if (lane >= o) incl += n;
    }
    counts[row * 64 + lane] = incl - v;
    if (lane == 63) nval[row] = incl;
}

__global__ __launch_bounds__(256) void scatter_kernel(const unsigned int* __restrict__ mask,
                                                      const int* __restrict__ offsets,
                                                      const float* __restrict__ gt,
                                                      const float* __restrict__ pred,
                                                      h2* __restrict__ val) {
    int cglob = blockIdx.x;        // 0..1023 (chunk of 8192 px)
    int b  = cglob >> 6;
    int t = threadIdx.x;
    __shared__ unsigned int svb[256];
    __shared__ int swoff[256];
    __shared__ int wsum[4];
    unsigned int vb = ~mask[(size_t)cglob * 256 + t];
    svb[t] = vb;
    int cnt = __popc(vb);
    int lane = t & 63, wid = t >> 6;
    int incl = cnt;
    for (int o = 1; o < 64; o <<= 1) {
        int n = __shfl_up(incl, o);
        if (lane >= o) incl += n;
    }
    if (lane == 63) wsum[wid] = incl;
    __syncthreads();
    int woff = 0;
    for (int i = 0; i < wid; i++) woff += wsum[i];
    swoff[t] = woff + incl - cnt;
    __syncthreads();
    size_t rowb = (size_t)b << 19;
    int chunkbase = offsets[cglob];
    size_t gbase = rowb + (size_t)(cglob & 63) * 8192;
    int bit = t & 31;
    unsigned int below = (bit == 0) ? 0u : ((1u << bit) - 1u);
    #pragma unroll 4
    for (int i = 0; i < 32; ++i) {
        int e = i * 256 + t;
        unsigned int bits = svb[i * 8 + (t >> 5)];
        if ((bits >> bit) & 1u) {
            int rank = chunkbase + swoff[i * 8 + (t >> 5)] + __popc(bits & below);
            size_t src = gbase + e;
            h2 o; o.x = (_Float16)gt[src]; o.y = (_Float16)pred[src];
            val[rowb + rank] = o;
        }
    }
}

__device__ __forceinline__ float fget(const f4& v, int k) {
    switch (k) { case 0: return v.x; case 1: return v.y; case 2: return v.z; default: return v.w; }
}

// 8 px/thread, 4096 blocks; rows {2x,2x+1} -> XCD x (blockIdx%8 heuristic).
__global__ __launch_bounds__(256) void loss_kernel(const float* __restrict__ pred,
                                                   const float* __restrict__ gt,
                                                   const float* __restrict__ ur,
                                                   const unsigned int* __restrict__ mask,
                                                   const h2* __restrict__ val,
                                                   const int* __restrict__ nv_arr,
                                                   double* __restrict__ acc_ls,
                                                   double* __restrict__ acc_ss,
                                                   unsigned int* __restrict__ cnt_nz,
                                                   unsigned int* __restrict__ cnt_zz) {
    int t = threadIdx.x;
    int bid = blockIdx.x;                       // 4096 blocks
    int b = ((bid & 7) << 1) | ((bid >> 3) & 1);
    int chunk = bid >> 4;                       // 256 chunks per row
    size_t rowb = (size_t)b << 19;
    int n0 = (chunk << 11) + t * 8;
    size_t g0 = rowb + (size_t)n0;
    unsigned int bits =
        (__builtin_nontemporal_load(&mask[g0 >> 5]) >> ((t & 3) << 3)) & 0xFFu;
    int nv = nv_arr[b];
    float fnv = (float)nv;
    f4 U[2], G[2], P[2];
    const f4* up = (const f4*)(ur + g0);
    const f4* gp = (const f4*)(gt + g0);
    const f4* pp = (const f4*)(pred + g0);
    #pragma unroll
    for (int i = 0; i < 2; ++i) {
        U[i] = __builtin_nontemporal_load(up + i);
        G[i] = __builtin_nontemporal_load(gp + i);
        P[i] = __builtin_nontemporal_load(pp + i);
    }
    float ls = 0.f, ss = 0.f;
    int cnz = 0, czz = 0;
    #pragma unroll
    for (int j = 0; j < 8; ++j) {
        if ((bits >> j) & 1u) {                 // invalid pixel
            float urv = fget(U[j >> 2], j & 3);
            int u = min((int)(urv * fnv), nv - 1);
            h2 v = val[rowb + (size_t)u];
            float vx = (float)v.x, vy = (float)v.y;
            float gc = fget(G[j >> 2], j & 3);
            float pc = fget(P[j >> 2], j & 3);
            float d = pc - vy;
            if (gc >= 1.02f * vx)      { ls += __logf(1.f + __expf(-d)); ++cnz; }
            else if (vx > 1.02f * gc)  { ls += __logf(1.f + __expf( d)); ++cnz; }
            else                       { ss += d * d; ++czz; }
        }
    }
    int lane = t & 63, wid = t >> 6;
    __shared__ double sd[4];
    __shared__ unsigned int si[4];
    double lsd = (double)ls, ssd = (double)ss;
    for (int o = 32; o > 0; o >>= 1) lsd += __shfl_down(lsd, o);
    if (lane == 0) sd[wid] = lsd;
    __syncthreads();
    if (t == 0) atomicAdd(&acc_ls[bid & 63], sd[0]+sd[1]+sd[2]+sd[3]);
    __syncthreads();
    for (int o = 32; o > 0; o >>= 1) ssd += __shfl_down(ssd, o);
    if (lane == 0) sd[wid] = ssd;
    __syncthreads();
    if (t == 0) atomicAdd(&acc_ss[bid & 63], sd[0]+sd[1]+sd[2]+sd[3]);
    __syncthreads();
    for (int o = 32; o > 0; o >>= 1) cnz += __shfl_down(cnz, o);
    if (lane == 0) si[wid] = (unsigned int)cnz;
    __syncthreads();
    if (t == 0) atomicAdd(&cnt_nz[bid & 63], si[0]+si[1]+si[2]+si[3]);
    __syncthreads();
    for (int o = 32; o > 0; o >>= 1) czz += __shfl_down(czz, o);
    if (lane == 0) si[wid] = (unsigned int)czz;
    __syncthreads();
    if (t == 0) atomicAdd(&cnt_zz[bid & 63], si[0]+si[1]+si[2]+si[3]);
}

__global__ void finalize_kernel(const double* __restrict__ acc_ls,
                                const double* __restrict__ acc_ss,
                                const unsigned int* __restrict__ cnt_nz,
                                const unsigned int* __restrict__ cnt_zz,
                                float* __restrict__ out) {
    int t = threadIdx.x;
    double l = acc_ls[t], s2 = acc_ss[t];
    unsigned int a = cnt_nz[t], c = cnt_zz[t];
    for (int o = 32; o > 0; o >>= 1) {
        l  += __shfl_down(l, o);
        s2 += __shfl_down(s2, o);
        a  += __shfl_down(a, o);
        c  += __shfl_down(c, o);
    }
    if (t == 0) out[0] = (float)(l / (double)a + s2 / (double)c);
}

extern "C" void kernel_launch(void* const* d_in, const int* in_sizes, int n_in,
                              void* d_out, int out_size, void* d_ws, size_t ws_size,
                              hipStream_t stream) {
    const float* pred = (const float*)d_in[0];
    const float* gt   = (const float*)d_in[1];
    const float* img  = (const float*)d_in[2];
    const float* ur   = (const float*)d_in[3];
    float* out = (float*)d_out;

    char* ws = (char*)d_ws;
    double*       sum_part = (double*)(ws + 0);
    double*       acc_ls   = (double*)(ws + 512);
    double*       acc_ss   = (double*)(ws + 1024);
    unsigned int* cnt_nz   = (unsigned int*)(ws + 1536);
    unsigned int* cnt_zz   = (unsigned int*)(ws + 1792);
    int*          nval     = (int*)(ws + 2048);
    int*          counts   = (int*)(ws + 4096);
    unsigned int* mask     = (unsigned int*)(ws + 8192);
    h2*           val      = (h2*)(ws + (1 << 21));
    _Float16*     tw       = (_Float16*)(ws + (1 << 21));   // aliases val (pre-scatter)

    (void)hipMemsetAsync(ws, 0, 8192, stream);
    tw_sum_kernel <<<2048, 256, 0, stream>>>(img, sum_part, tw);
    mask_kernel   <<<8192, 256, 0, stream>>>(tw, sum_part, mask, counts);
    scan_kernel   <<<1, 1024, 0, stream>>>(counts, nval);
    scatter_kernel<<<1024, 256, 0, stream>>>(mask, counts, gt, pred, val);
    loss_kernel   <<<4096, 256, 0, stream>>>(pred, gt, ur, mask, val, nval,
                                             acc_ls, acc_ss, cnt_nz, cnt_zz);
    finalize_kernel<<<1, 64, 0, stream>>>(acc_ls, acc_ss, cnt_nz, cnt_zz, out);
}